// Round 3
// baseline (392.277 us; speedup 1.0000x reference)
//
#include <hip/hip_runtime.h>

// StructuredLinear: mask[o,i] = (o/64 == i/64) -> 64 independent 64x64
// diagonal-block GEMMs. x:[8192,4096] f32, w:[4096,4096] f32, out:[8192,4096].
//
// R1 lesson: 4x4 register tiling was LDS-ISSUE-bound (per-CU ds_read model
// 90us ~= 95us measured; VALUBusy 48%, HBM 27%, conflicts 0).
// R2/R3 design: lane = row. Each lane holds its whole 64-float x row in VGPRs
// (16 ds_read_b128). w[o][k] is wave-uniform -> forced through readfirstlane
// so the backend emits s_load (SMEM pipe), inner loop is pure v_fmac_f32
// (SGPR x VGPR). Output transposed through LDS for coalesced stores.
// LDS ops/thread: 28 (vs R1's 128) -> LDS pipe ~18us, fmac ~27us, HBM ~33us.

constexpr int IN_F  = 4096;
constexpr int OUT_F = 4096;
constexpr int BLK   = 64;   // diagonal block size
constexpr int NBLK  = 64;
constexpr int ROWS  = 64;   // x rows per workgroup
constexpr int PAD   = 68;   // LDS row stride (floats): 272B, b128-aligned.
                            // b128 reads at stride 68: lanes 0..7 start banks
                            // {0,4,..,28}, cover all 32 -> conflict-free.

__global__ __launch_bounds__(256, 4)
void block_diag_sgemm(const float* __restrict__ x,
                      const float* __restrict__ w,
                      float* __restrict__ out)
{
    __shared__ float xs[ROWS * PAD];   // x tile, shared by all 4 waves
    __shared__ float os[ROWS * PAD];   // output transpose buffer

    const int blk  = blockIdx.y;          // diagonal block 0..63
    const int r0   = blockIdx.x * ROWS;   // row-tile base
    const int c0   = blk * BLK;           // in-col AND out-col base
    const int tid  = threadIdx.x;
    const int lane = tid & 63;
    const int wave = tid >> 6;            // 0..3: owns out cols [wave*16, wave*16+16)

    // ---- stage x tile (64 rows x 64 cols) into LDS, coalesced ----
    // 1024 float4s / 256 threads = 4 each; per instr: 4 rows x 256B segments.
#pragma unroll
    for (int j = 0; j < 4; ++j) {
        const int e   = j * 256 + tid;    // float4 index 0..1023
        const int row = e >> 4;
        const int c4  = e & 15;
        const float4 v = *reinterpret_cast<const float4*>(
            &x[(size_t)(r0 + row) * IN_F + c0 + c4 * 4]);
        *reinterpret_cast<float4*>(&xs[row * PAD + c4 * 4]) = v;
    }
    __syncthreads();

    // ---- each lane pulls its own row into VGPRs: 16 ds_read_b128 ----
    float4 xr[16];
#pragma unroll
    for (int k4 = 0; k4 < 16; ++k4)
        xr[k4] = *reinterpret_cast<const float4*>(&xs[lane * PAD + k4 * 4]);

    // ---- compute: out[r0+lane][c0+o0+oo] for oo in 0..15 ----
    // readfirstlane forces the w row offset into an SGPR so the loads select
    // the SMEM path (s_load_dwordx*) -- without it, tid>>6 is "divergent" to
    // the compiler and these become 256 broadcast global_loads per thread.
    const int o0 = wave * 16;
    float acc[16];
#pragma unroll
    for (int oo = 0; oo < 16; ++oo) {
        const int woff = __builtin_amdgcn_readfirstlane(
            (c0 + o0 + oo) * IN_F + c0);
        const float* __restrict__ wr = w + woff;
        float a0 = 0.f, a1 = 0.f, a2 = 0.f, a3 = 0.f;  // 4 chains hide fmac latency
#pragma unroll
        for (int k4 = 0; k4 < 16; ++k4) {
            a0 += wr[k4 * 4 + 0] * xr[k4].x;
            a1 += wr[k4 * 4 + 1] * xr[k4].y;
            a2 += wr[k4 * 4 + 2] * xr[k4].z;
            a3 += wr[k4 * 4 + 3] * xr[k4].w;
        }
        acc[oo] = (a0 + a1) + (a2 + a3);
    }

    // ---- transpose through LDS for coalesced float4 stores ----
#pragma unroll
    for (int oo4 = 0; oo4 < 4; ++oo4) {
        const float4 v = make_float4(acc[oo4 * 4 + 0], acc[oo4 * 4 + 1],
                                     acc[oo4 * 4 + 2], acc[oo4 * 4 + 3]);
        *reinterpret_cast<float4*>(&os[lane * PAD + o0 + oo4 * 4]) = v;
    }
    __syncthreads();
#pragma unroll
    for (int j = 0; j < 4; ++j) {
        const int e   = j * 256 + tid;
        const int row = e >> 4;
        const int c4  = e & 15;
        const float4 v = *reinterpret_cast<const float4*>(&os[row * PAD + c4 * 4]);
        *reinterpret_cast<float4*>(&out[(size_t)(r0 + row) * OUT_F + c0 + c4 * 4]) = v;
    }
}

extern "C" void kernel_launch(void* const* d_in, const int* in_sizes, int n_in,
                              void* d_out, int out_size, void* d_ws, size_t ws_size,
                              hipStream_t stream) {
    const float* x = (const float*)d_in[0];
    const float* w = (const float*)d_in[1];
    // d_in[2] (mask) is baked in: 64x64 block-diagonal.
    float* out = (float*)d_out;

    const int nrows = in_sizes[0] / IN_F;   // 8192
    dim3 grid(nrows / ROWS, NBLK);          // 128 x 64
    block_diag_sgemm<<<grid, dim3(256, 1, 1), 0, stream>>>(x, w, out);
}

// Round 5
// 303.243 us; speedup vs baseline: 1.2936x; 1.2936x over previous
//
#include <hip/hip_runtime.h>

// StructuredLinear: mask[o,i] = (o/64 == i/64) -> 64 independent 64x64
// diagonal-block GEMMs. x:[8192,4096] f32, w:[4096,4096] f32, out:[8192,4096].
//
// R1: fp32 VALU, 4x4 reg tile -> LDS-issue bound, 95us.
// R3: scalar-w path -> serial SMEM stalls, 175us. fp32 operand delivery is
//     the structural tax -> switch to MFMA.
// R4/R5: split-bf16 MFMA. x = xh + xl, w = wh + wl (bf16 RNE + residual),
//     out = xh*wh + xh*wl + xl*wh + xl*wl via mfma_f32_32x32x16_bf16, fp32
//     accum. Error ~1e-4 absmax (harness passed 0.125 in R3).
//     Compute ~7us MFMA + ~11us LDS + ~6us cvt -> memory-bound (~210MB HBM).

constexpr int IN_F  = 4096;
constexpr int OUT_F = 4096;
constexpr int NBLK  = 64;   // diagonal blocks
constexpr int TROWS = 64;   // x rows per workgroup

typedef __attribute__((ext_vector_type(8)))  short short8;   // 8 bf16 (4 VGPR)
typedef __attribute__((ext_vector_type(4)))  short short4v;  // 4 bf16 (8B)
typedef __attribute__((ext_vector_type(16))) float f32x16;   // 32x32 acc frag

static __device__ __forceinline__ short f2bf_rne(float f) {
    union { float f; unsigned u; } v; v.f = f;
    unsigned r = v.u + 0x7FFFu + ((v.u >> 16) & 1u);   // round-nearest-even
    return (short)(r >> 16);
}
static __device__ __forceinline__ float bf2f(short h) {
    union { unsigned u; float f; } v; v.u = ((unsigned)(unsigned short)h) << 16;
    return v.f;
}

// LDS bf16 tiles are [64 rows][64 cols] = 128B/row: naive frag reads (32 lanes,
// fixed 16B chunk, rows 0..31) would be 32-way bank conflicts (G4). XOR-swizzle
// the 16B-chunk index with (row&7): each 8-row group covers all 32 banks once
// -> conflict-free floor on both ds_write (staging) and ds_read_b128 (frags).
static __device__ __forceinline__ int swz(int row, int chunk) {  // -> short index
    return row * 64 + ((chunk ^ (row & 7)) << 3);
}

__global__ __launch_bounds__(256, 4)
void block_diag_mfma(const float* __restrict__ x,
                     const float* __restrict__ w,
                     float* __restrict__ out)
{
    __shared__ short xh[64 * 64], xl[64 * 64];   // 8 KB each
    __shared__ short wh[64 * 64], wl[64 * 64];   // total 32 KB

    const int blk = blockIdx.y;
    const int r0  = blockIdx.x * TROWS;
    const int c0  = blk * 64;              // in-col AND out-col base
    const int tid = threadIdx.x;

    // ---- stage + split-convert x tile and w diagonal block ----
    // 1024 float4s each / 256 threads = 4 iters; global reads fully coalesced.
#pragma unroll
    for (int j = 0; j < 4; ++j) {
        const int e   = j * 256 + tid;     // float4 index 0..1023
        const int row = e >> 4;
        const int c4  = e & 15;            // float4 column
        const int sidx = swz(row, c4 >> 1) + (c4 & 1) * 4;  // 8B sub-chunk

        const float4 gx = *reinterpret_cast<const float4*>(
            &x[(size_t)(r0 + row) * IN_F + c0 + c4 * 4]);
        short4v h, l;
        h.x = f2bf_rne(gx.x); l.x = f2bf_rne(gx.x - bf2f(h.x));
        h.y = f2bf_rne(gx.y); l.y = f2bf_rne(gx.y - bf2f(h.y));
        h.z = f2bf_rne(gx.z); l.z = f2bf_rne(gx.z - bf2f(h.z));
        h.w = f2bf_rne(gx.w); l.w = f2bf_rne(gx.w - bf2f(h.w));
        *reinterpret_cast<short4v*>(&xh[sidx]) = h;
        *reinterpret_cast<short4v*>(&xl[sidx]) = l;

        const float4 gw = *reinterpret_cast<const float4*>(
            &w[(size_t)(c0 + row) * IN_F + c0 + c4 * 4]);
        h.x = f2bf_rne(gw.x); l.x = f2bf_rne(gw.x - bf2f(h.x));
        h.y = f2bf_rne(gw.y); l.y = f2bf_rne(gw.y - bf2f(h.y));
        h.z = f2bf_rne(gw.z); l.z = f2bf_rne(gw.z - bf2f(h.z));
        h.w = f2bf_rne(gw.w); l.w = f2bf_rne(gw.w - bf2f(h.w));
        *reinterpret_cast<short4v*>(&wh[sidx]) = h;
        *reinterpret_cast<short4v*>(&wl[sidx]) = l;
    }
    __syncthreads();

    // ---- MFMA: wave q owns quadrant (qr,qc) of the 64x64 output ----
    // A-frag lane l elem i = x[qr*32+(l&31)][ks*16 + 8*(l>>5) + i]
    // B-frag lane l elem i = w[qc*32+(l&31)][ks*16 + 8*(l>>5) + i]
    // (mfma computes D[m][n] = sum_k A[m][k]*B[k][n]; B-frag k-major = w^T)
    const int wave = tid >> 6, lane = tid & 63;
    const int qr = wave >> 1, qc = wave & 1;
    const int l31 = lane & 31, g = lane >> 5;
    const int arow = qr * 32 + l31;        // x row
    const int bcol = qc * 32 + l31;        // w row (= out col)

    f32x16 acc0 = {}, acc1 = {};           // 2 chains to halve MFMA dep depth
#pragma unroll
    for (int ks = 0; ks < 4; ++ks) {       // K = 64 in steps of 16
        const int chunk = ks * 2 + g;
        const short8 a_h = *reinterpret_cast<const short8*>(&xh[swz(arow, chunk)]);
        const short8 a_l = *reinterpret_cast<const short8*>(&xl[swz(arow, chunk)]);
        const short8 b_h = *reinterpret_cast<const short8*>(&wh[swz(bcol, chunk)]);
        const short8 b_l = *reinterpret_cast<const short8*>(&wl[swz(bcol, chunk)]);
        acc0 = __builtin_amdgcn_mfma_f32_32x32x16_bf16(a_h, b_h, acc0, 0, 0, 0);
        acc1 = __builtin_amdgcn_mfma_f32_32x32x16_bf16(a_h, b_l, acc1, 0, 0, 0);
        acc0 = __builtin_amdgcn_mfma_f32_32x32x16_bf16(a_l, b_h, acc0, 0, 0, 0);
        acc1 = __builtin_amdgcn_mfma_f32_32x32x16_bf16(a_l, b_l, acc1, 0, 0, 0);
    }

    // ---- epilogue: C/D layout col=lane&31, row=(reg&3)+8*(reg>>2)+4*g ----
    // Per store: lanes 0..31 -> 128B contiguous of row R, lanes 32..63 -> row
    // R+4. Two full cachelines per instruction -> coalesced enough.
    float* obase = &out[(size_t)(r0 + qr * 32) * OUT_F + c0 + qc * 32];
#pragma unroll
    for (int reg = 0; reg < 16; ++reg) {
        const int rq = (reg & 3) + 8 * (reg >> 2) + 4 * g;
        obase[(size_t)rq * OUT_F + l31] = acc0[reg] + acc1[reg];
    }
}

extern "C" void kernel_launch(void* const* d_in, const int* in_sizes, int n_in,
                              void* d_out, int out_size, void* d_ws, size_t ws_size,
                              hipStream_t stream) {
    const float* x = (const float*)d_in[0];
    const float* w = (const float*)d_in[1];
    // d_in[2] (mask) baked in: 64x64 block-diagonal.
    float* out = (float*)d_out;

    const int nrows = in_sizes[0] / IN_F;   // 8192
    dim3 grid(nrows / TROWS, NBLK);         // 128 x 64
    block_diag_mfma<<<grid, dim3(256, 1, 1), 0, stream>>>(x, w, out);
}